// Round 16
// baseline (608.738 us; speedup 1.0000x reference)
//
#include <hip/hip_runtime.h>
#include <stdint.h>

// GraphConvLayer: out[n,:] = W[type[n]] @ (A @ x)[n,:]
// N=16384, D=128, T=8.  A is 1 GiB f32 read exactly once -> HBM floor ~163us.
// Round 16 = Round 13 (best, 310us) with X moved out of LDS:
//  - X fragments load directly from L2-resident g_xT (plain 16B loads,
//    batched per phase, 64B-coalesced). No X DMA, no X LDS, no 4x LDS
//    read redundancy. LDS traffic/phase: 256KB -> 96KB.
//  - A: 3 DMA buffers (96KB) -> ONE barrier per phase (R10 schedule @ BK=128).
//  - A DMAs carry NT (aux=2) so the 1GiB stream doesn't evict g_xT from L2.
//  - sched_barrier(0x10F) fences pin VMEM order (X batch | A-DMA | compute)
//    so compiler X-waits never drain the A prefetch queue; DS/VALU/MFMA may
//    still float across to hide X's L2 latency.

#define N_NODES 16384
#define DIM     128
#define NTYPES  8
#define BM      64
#define BK      128
#define NT_K    (N_NODES / BK)   // 128 phases

typedef float  f32x4  __attribute__((ext_vector_type(4)));
typedef __bf16 bf16x8 __attribute__((ext_vector_type(8)));

__device__ __attribute__((aligned(16))) unsigned short g_xT[DIM * N_NODES];      // [d][n], 4 MiB bf16
__device__ __attribute__((aligned(16))) unsigned short g_Wb[NTYPES * DIM * DIM]; // [t][o][d], 256 KiB

__device__ __forceinline__ unsigned int f2b(float f) {
    unsigned int u = __float_as_uint(f);
    u += 0x7FFFu + ((u >> 16) & 1u);   // round-to-nearest-even
    return u >> 16;
}
#define BF_LO(u) __uint_as_float((unsigned int)(u) << 16)
#define BF_HI(u) __uint_as_float((unsigned int)(u) & 0xFFFF0000u)

__device__ __forceinline__ bf16x8 cvt8(const f32x4 lo, const f32x4 hi) {
    bf16x8 r;
    r[0] = (__bf16)lo[0]; r[1] = (__bf16)lo[1]; r[2] = (__bf16)lo[2]; r[3] = (__bf16)lo[3];
    r[4] = (__bf16)hi[0]; r[5] = (__bf16)hi[1]; r[6] = (__bf16)hi[2]; r[7] = (__bf16)hi[3];
    return r;
}

// ---------------- fused prep kernel ----------------
// blocks 0..63: xT transpose+convert; blocks 64..95: W convert.

__global__ void prep_all(const float* __restrict__ x, const float* __restrict__ w) {
    const int tid = threadIdx.x;
    if (blockIdx.x < 64) {
        int n = blockIdx.x * 256 + tid;
        const float* row = x + (size_t)n * DIM;
#pragma unroll
        for (int d0 = 0; d0 < DIM; d0 += 4) {
            float4 v = *(const float4*)(row + d0);
            g_xT[(d0 + 0) * N_NODES + n] = (unsigned short)f2b(v.x);
            g_xT[(d0 + 1) * N_NODES + n] = (unsigned short)f2b(v.y);
            g_xT[(d0 + 2) * N_NODES + n] = (unsigned short)f2b(v.z);
            g_xT[(d0 + 3) * N_NODES + n] = (unsigned short)f2b(v.w);
        }
    } else {
        int base = ((blockIdx.x - 64) * 256 + tid) * 16;
#pragma unroll
        for (int j = 0; j < 4; ++j) {
            float4 v = *(const float4*)(w + base + j * 4);
            ushort4 o;
            o.x = (unsigned short)f2b(v.x); o.y = (unsigned short)f2b(v.y);
            o.z = (unsigned short)f2b(v.z); o.w = (unsigned short)f2b(v.w);
            *(ushort4*)(g_Wb + base + j * 4) = o;
        }
    }
}

// ---------------- main fused kernel ----------------

#define ABYTES 32768   // A tile: 64 rows x 512B (f32; row-major, XOR-swizzled chunks)

// NT-hinted DMA (aux=2 = NT on gfx940+): A lines are single-use, keep L2 for X
#define GLOADNT(g, l) __builtin_amdgcn_global_load_lds(                         \
    (const __attribute__((address_space(1))) unsigned int*)(g),                 \
    (__attribute__((address_space(3))) unsigned int*)(l), 16, 0, 2)

// 4 DMA calls per wave per tile; call j covers rows j*16 + 2w + (l>>5)
#define ISSUE_A(Ab) do {                                                        \
    GLOADNT(gA0, (Ab) + wq);          GLOADNT(gA1, (Ab) +  8192 + wq);          \
    GLOADNT(gA2, (Ab) + 16384 + wq);  GLOADNT(gA3, (Ab) + 24576 + wq);          \
    gA0 += BK; gA1 += BK; gA2 += BK; gA3 += BK;                                 \
} while (0)

// one k-substep (32 k): A frag from LDS (2 f32x4 + cvt) x 4 register X frags
#define KSUB(Ab, kc, X0_, X1_, X2_, X3_) do {                                   \
    f32x4 _e = *(const f32x4*)((Ab) + aoE + (kc) * 128);                        \
    f32x4 _o = *(const f32x4*)((Ab) + aoO + (kc) * 128);                        \
    bf16x8 _a = cvt8(_e, _o);                                                   \
    acc0 = __builtin_amdgcn_mfma_f32_16x16x32_bf16(_a, X0_, acc0, 0, 0, 0);     \
    acc1 = __builtin_amdgcn_mfma_f32_16x16x32_bf16(_a, X1_, acc1, 0, 0, 0);     \
    acc2 = __builtin_amdgcn_mfma_f32_16x16x32_bf16(_a, X2_, acc2, 0, 0, 0);     \
    acc3 = __builtin_amdgcn_mfma_f32_16x16x32_bf16(_a, X3_, acc3, 0, 0, 0);     \
} while (0)

// SB mask 0x10F: ALU|VALU|SALU|MFMA|DS_READ may cross; VMEM pinned.
#define SB() __builtin_amdgcn_sched_barrier(0x10F)

// phase t: vmcnt(4) [t's 4 DMAs done; t+2's 4 stay in flight] -> barrier ->
// X batch loads (16x16B from L2) -> issue t+2's A -> compute.
#define PH_I(Ac, Ai) do {                                                       \
    asm volatile("s_waitcnt vmcnt(4)" ::: "memory");                            \
    __builtin_amdgcn_s_barrier();                                               \
    bf16x8 x00 = *(const bf16x8*)(bx0);      bf16x8 x01 = *(const bf16x8*)(bx1);      \
    bf16x8 x02 = *(const bf16x8*)(bx2);      bf16x8 x03 = *(const bf16x8*)(bx3);      \
    bf16x8 x10 = *(const bf16x8*)(bx0 + 32); bf16x8 x11 = *(const bf16x8*)(bx1 + 32); \
    bf16x8 x12 = *(const bf16x8*)(bx2 + 32); bf16x8 x13 = *(const bf16x8*)(bx3 + 32); \
    bf16x8 x20 = *(const bf16x8*)(bx0 + 64); bf16x8 x21 = *(const bf16x8*)(bx1 + 64); \
    bf16x8 x22 = *(const bf16x8*)(bx2 + 64); bf16x8 x23 = *(const bf16x8*)(bx3 + 64); \
    bf16x8 x30 = *(const bf16x8*)(bx0 + 96); bf16x8 x31 = *(const bf16x8*)(bx1 + 96); \
    bf16x8 x32 = *(const bf16x8*)(bx2 + 96); bf16x8 x33 = *(const bf16x8*)(bx3 + 96); \
    SB();                                                                       \
    ISSUE_A(Ai);                                                                \
    SB();                                                                       \
    KSUB(Ac, 0, x00, x01, x02, x03);                                            \
    KSUB(Ac, 1, x10, x11, x12, x13);                                            \
    KSUB(Ac, 2, x20, x21, x22, x23);                                            \
    KSUB(Ac, 3, x30, x31, x32, x33);                                            \
    bx0 += BK; bx1 += BK; bx2 += BK; bx3 += BK;                                 \
} while (0)

#define PH_N(Ac, VM) do {                                                       \
    asm volatile("s_waitcnt vmcnt(" VM ")" ::: "memory");                       \
    __builtin_amdgcn_s_barrier();                                               \
    bf16x8 x00 = *(const bf16x8*)(bx0);      bf16x8 x01 = *(const bf16x8*)(bx1);      \
    bf16x8 x02 = *(const bf16x8*)(bx2);      bf16x8 x03 = *(const bf16x8*)(bx3);      \
    bf16x8 x10 = *(const bf16x8*)(bx0 + 32); bf16x8 x11 = *(const bf16x8*)(bx1 + 32); \
    bf16x8 x12 = *(const bf16x8*)(bx2 + 32); bf16x8 x13 = *(const bf16x8*)(bx3 + 32); \
    bf16x8 x20 = *(const bf16x8*)(bx0 + 64); bf16x8 x21 = *(const bf16x8*)(bx1 + 64); \
    bf16x8 x22 = *(const bf16x8*)(bx2 + 64); bf16x8 x23 = *(const bf16x8*)(bx3 + 64); \
    bf16x8 x30 = *(const bf16x8*)(bx0 + 96); bf16x8 x31 = *(const bf16x8*)(bx1 + 96); \
    bf16x8 x32 = *(const bf16x8*)(bx2 + 96); bf16x8 x33 = *(const bf16x8*)(bx3 + 96); \
    SB();                                                                       \
    KSUB(Ac, 0, x00, x01, x02, x03);                                            \
    KSUB(Ac, 1, x10, x11, x12, x13);                                            \
    KSUB(Ac, 2, x20, x21, x22, x23);                                            \
    KSUB(Ac, 3, x30, x31, x32, x33);                                            \
    bx0 += BK; bx1 += BK; bx2 += BK; bx3 += BK;                                 \
} while (0)

__global__ __launch_bounds__(512, 1) void gconv_main(
    const float* __restrict__ adj,
    const int* __restrict__ types,
    float* __restrict__ out)
{
    __shared__ __align__(16) unsigned char lds[3 * ABYTES];   // 98304 B (agg reuse)
    unsigned char* Ab0 = lds;
    unsigned char* Ab1 = lds + ABYTES;
    unsigned char* Ab2 = lds + 2 * ABYTES;

    const int tid  = threadIdx.x;
    const int w    = tid >> 6;          // 0..7
    const int l    = tid & 63;
    const int m0   = blockIdx.x * BM;

    const int mrow = (w & 3) * 16;      // wave's 16 output rows (of 64)
    const int ncol = (w >> 2) * 64;     // wave's 64 output cols (of 128)

    f32x4 acc0 = {}, acc1 = {}, acc2 = {}, acc3 = {};

    // ---- A DMA source pointers (pre-swizzled; linear LDS dest = row-major
    // 64x512B; read side XORs the same involution, m173/T2) ----
    // call j: row = j*16 + 2w + (l>>5); src chunk = (l&31) ^ (row&7)
    const int arw = 2 * w + (l >> 5);
    const float* gA0 = adj + (size_t)(m0 + arw) * N_NODES
                     + (((l & 31) ^ (arw & 7)) << 2);
    const float* gA1 = gA0 + (size_t)16 * N_NODES;
    const float* gA2 = gA0 + (size_t)32 * N_NODES;
    const float* gA3 = gA0 + (size_t)48 * N_NODES;
    const int wq = w << 10;             // wave's 1KB slot within each 8KB call round

    // ---- A compute-side offsets: row r = mrow+(l&15) (r&7 = l&7);
    // ksub kc reads logical chunks kc*8+2h, +1 (h = l>>4); phys = logical^(l&7)
    const int r   = mrow + (l & 15);
    const int aoE = r * 512 + ((((l >> 4) * 2)     ^ (l & 7)) << 4);
    const int aoO = r * 512 + ((((l >> 4) * 2 + 1) ^ (l & 7)) << 4);

    // ---- X direct-from-L2 pointers: frag nt at col ncol+nt*16+(l&15),
    // k-granule (l>>4)*8; 4 lanes share each 64B segment. Advance BK/phase.
    const unsigned short* bx0 = g_xT + (size_t)(ncol +  0 + (l & 15)) * N_NODES + ((l >> 4) << 3);
    const unsigned short* bx1 = g_xT + (size_t)(ncol + 16 + (l & 15)) * N_NODES + ((l >> 4) << 3);
    const unsigned short* bx2 = g_xT + (size_t)(ncol + 32 + (l & 15)) * N_NODES + ((l >> 4) << 3);
    const unsigned short* bx3 = g_xT + (size_t)(ncol + 48 + (l & 15)) * N_NODES + ((l >> 4) << 3);

    // ---- prologue: tiles 0,1 in flight (8 DMA calls/wave outstanding) ----
    ISSUE_A(Ab0);
    ISSUE_A(Ab1);

    // ---- 128 phases: 42 x 3 issuing (t=0..125) + 2 tail ----
    for (int i = 0; i < 42; ++i) {
        PH_I(Ab0, Ab2);                 // t=3i   : compute buf0, issue t+2 -> buf2
        PH_I(Ab1, Ab0);                 // t=3i+1 : issue -> buf0
        PH_I(Ab2, Ab1);                 // t=3i+2 : issue -> buf1
    }
    PH_N(Ab0, "4");                     // t=126 (127's 4 DMAs in flight)
    PH_N(Ab1, "0");                     // t=127
    __syncthreads();                    // drain before reusing LDS as agg

    // ---- epilogue: acc -> LDS agg (f32), then per-row W[type] dots ----
    float* agg = (float*)lds;   // [64][132] = 33792 B
#pragma unroll
    for (int rr = 0; rr < 4; ++rr) {
        const int gr = (mrow + (l >> 4) * 4 + rr) * 132 + ncol + (l & 15);
        agg[gr +  0] = acc0[rr];
        agg[gr + 16] = acc1[rr];
        agg[gr + 32] = acc2[rr];
        agg[gr + 48] = acc3[rr];
    }
    __syncthreads();

    const int rbase = w * 8;   // 8 rows per wave
    for (int rr = 0; rr < 8; ++rr) {
        const int rw = rbase + rr;
        const int nn = m0 + rw;
        const int ty = types[nn];                      // wave-uniform
        const unsigned short* Wt = g_Wb + ty * (DIM * DIM);
        const int o0 = l * 2;
        const float* aggRow = agg + rw * 132;
        float s0 = 0.f, s1 = 0.f;
#pragma unroll
        for (int d0 = 0; d0 < DIM; d0 += 8) {
            float4 ga = *(const float4*)(aggRow + d0);
            float4 gb = *(const float4*)(aggRow + d0 + 4);
            uint4 wa = *(const uint4*)(Wt + o0 * DIM + d0);
            uint4 wb = *(const uint4*)(Wt + (o0 + 1) * DIM + d0);
            s0 += ga.x * BF_LO(wa.x) + ga.y * BF_HI(wa.x) + ga.z * BF_LO(wa.y) + ga.w * BF_HI(wa.y);
            s0 += gb.x * BF_LO(wa.z) + gb.y * BF_HI(wa.z) + gb.z * BF_LO(wa.w) + gb.w * BF_HI(wa.w);
            s1 += ga.x * BF_LO(wb.x) + ga.y * BF_HI(wb.x) + ga.z * BF_LO(wb.y) + ga.w * BF_HI(wb.y);
            s1 += gb.x * BF_LO(wb.z) + gb.y * BF_HI(wb.z) + gb.z * BF_LO(wb.w) + gb.w * BF_HI(wb.w);
        }
        float2 res; res.x = s0; res.y = s1;
        *(float2*)(out + (size_t)nn * DIM + o0) = res;
    }
}

// ---------------- launch ----------------

extern "C" void kernel_launch(void* const* d_in, const int* in_sizes, int n_in,
                              void* d_out, int out_size, void* d_ws, size_t ws_size,
                              hipStream_t stream) {
    const float* x     = (const float*)d_in[0];
    const int*   types = (const int*)d_in[1];
    const float* adj   = (const float*)d_in[2];
    const float* wt    = (const float*)d_in[3];
    float* out = (float*)d_out;

    hipLaunchKernelGGL(prep_all, dim3(96), dim3(256), 0, stream, x, wt);
    hipLaunchKernelGGL(gconv_main, dim3(N_NODES / BM), dim3(512), 0, stream, adj, types, out);
}